// Round 9
// baseline (225.265 us; speedup 1.0000x reference)
//
#include <hip/hip_runtime.h>

// NMS3D (4,4,32,256,256) fp32, strict 26-neighbor max.
// R15: split-stage block — phase-B's DMA drain hides under phase-A's compute,
// with the store-safe counted-wait ordering learned from R13.
// Session state: R9 (stage->drain->compute, 36KiB, 4/CU) = 62us slice champion;
// pipelines R8/R12/R13 = 85/80/81; geometry flat; swizzle hurts; store mode
// neutral (R14). Floor = (89+134)MB / 6.3TB/s = 35us; copy ubench proves HW
// does 6.3 TB/s on a mixed stream, so not roofline yet.
// R13's lesson operationalized: vmcnt retires oldest-first, so a wait only
// stays store-free if ALL awaited DMAs were issued BEFORE any store. Hence:
//   stage A (9 DMA/wave: rows 0-5 x 6 planes = 36 KiB)
//   stage B (6 DMA/wave: rows 6-9 x 6 planes = 24 KiB)   <- all DMAs up front
//   vmcnt(6) + barrier      : A resident, B still in flight
//   compute rows 0-3        : 4 nt-stores (now newest in FIFO)
//   vmcnt(4) + barrier      : B resident; the 4 stores stay un-waited
//   compute rows 4-7
// Exposed drain per output row = drain(36K)/8 rows, HALF of R9's. 60 KiB ->
// 2 blocks/CU, 4096 blocks (16 generations/CU of turnover). Read amp 1.875x.
// Math verified absmax 0.0 in R6-R14: separable vertical max + lane shuffles.

typedef float v4f __attribute__((ext_vector_type(4)));

constexpr int W  = 256;
constexpr int H  = 256;
constexpr int D  = 32;
constexpr int SH = W;
constexpr int SD = W * H;
constexpr int KD = 4;                  // d outputs per block (1 per wave)
constexpr int HC = 8;                  // h output rows per block
constexpr int BC = 16;                 // B*CH
constexpr int DG = D / KD;             // 8
constexpr int HG = H / HC;             // 32
constexpr int NPL = KD + 2;            // 6 staged planes
constexpr int NR  = HC + 2;            // 10 staged rows per plane
// phase A = rows 0..5 of each plane (36 rows), phase B = rows 6..9 (24 rows)

__device__ __forceinline__ v4f vmax4(v4f a, v4f b) {
    return (v4f){fmaxf(a.x, b.x), fmaxf(a.y, b.y), fmaxf(a.z, b.z), fmaxf(a.w, b.w)};
}

__global__ __launch_bounds__(256, 2) void nms3d_kernel(const float* __restrict__ x,
                                                       float* __restrict__ out) {
    __shared__ float lds[NPL * NR * W];   // 60 KiB -> 2 blocks/CU

    const int blk  = blockIdx.x;
    const int wv   = threadIdx.x >> 6;   // 0..3
    const int lane = threadIdx.x & 63;
    const int hc   = blk & (HG - 1);            // fastest: h-neighbors share halo in L2
    const int dg   = (blk >> 5) & (DG - 1);
    const int bc   = blk >> 8;
    const int d0   = dg * KD;
    const int h0   = hc * HC;

    const float* vol = x + bc * (D * SD);

    // ---- stage phase A: 36 rows (r=0..5 of each plane); wave wv -> t=wv*9+u ----
    #pragma unroll
    for (int u = 0; u < 9; ++u) {
        const int t = wv * 9 + u;
        const int j = t / 6;               // plane 0..5
        const int r = t - j * 6;           // row   0..5
        int p = d0 - 1 + j;  p = p < 0 ? 0 : (p > D - 1 ? D - 1 : p);
        int hh = h0 - 1 + r; hh = hh < 0 ? 0 : (hh > H - 1 ? H - 1 : hh);
        const float* gp = vol + p * SD + hh * SH + (lane << 2);
        __builtin_amdgcn_global_load_lds(
            (const __attribute__((address_space(1))) unsigned int*)gp,
            (__attribute__((address_space(3))) unsigned int*)&lds[(j * NR + r) * W],
            16, 0, 0);
    }
    // ---- stage phase B: 24 rows (r=6..9 of each plane); wave wv -> t=wv*6+u ----
    #pragma unroll
    for (int u = 0; u < 6; ++u) {
        const int t = wv * 6 + u;
        const int j = t / 4;               // plane 0..5
        const int r = 6 + (t - j * 4);     // row   6..9
        int p = d0 - 1 + j;  p = p < 0 ? 0 : (p > D - 1 ? D - 1 : p);
        int hh = h0 - 1 + r; hh = hh > H - 1 ? H - 1 : hh;   // r>=6 -> no low clamp
        const float* gp = vol + p * SD + hh * SH + (lane << 2);
        __builtin_amdgcn_global_load_lds(
            (const __attribute__((address_space(1))) unsigned int*)gp,
            (__attribute__((address_space(3))) unsigned int*)&lds[(j * NR + r) * W],
            16, 0, 0);
    }
    __builtin_amdgcn_sched_barrier(0);
    // FIFO/wave (oldest->newest): [A:9][B:6]. vmcnt(6): A resident, B in flight.
    asm volatile("s_waitcnt vmcnt(6)" ::: "memory");
    __builtin_amdgcn_s_barrier();              // all waves' A resident
    __builtin_amdgcn_sched_barrier(0);         // no LDS-read hoist above this

    // ---- compute: wave wv handles output plane d = d0 + wv ----
    const int d = d0 + wv;
    const bool dv = (d > 0) && (d < D - 1);
    float* ovol = out + bc * (D * SD) + d * SD + (lane << 2);

    const float* Lm = lds + (wv * NR) * W + (lane << 2);        // plane d-1
    const float* L0 = lds + ((wv + 1) * NR) * W + (lane << 2);  // plane d
    const float* Lp = lds + ((wv + 2) * NR) * W + (lane << 2);  // plane d+1

    // rolling 3-row window per plane, slot = (row mod 3), fully unrolled
    v4f rm[3], r0[3], rp[3];
    rm[0] = *(const v4f*)(Lm + 0 * W); r0[0] = *(const v4f*)(L0 + 0 * W); rp[0] = *(const v4f*)(Lp + 0 * W);
    rm[1] = *(const v4f*)(Lm + 1 * W); r0[1] = *(const v4f*)(L0 + 1 * W); rp[1] = *(const v4f*)(Lp + 1 * W);

    #pragma unroll
    for (int i = 0; i < HC; ++i) {
        if (i == 4) {
            // phase boundary: rows 4-7 read staged rows 6..9 (phase B).
            // FIFO now: [B: <=6][A-stores: 4]. vmcnt(4) -> B resident,
            // the 4 nt-stores (newest) stay un-waited (R13 lesson).
            __builtin_amdgcn_sched_barrier(0);
            asm volatile("s_waitcnt vmcnt(4)" ::: "memory");
            __builtin_amdgcn_s_barrier();          // all waves' B resident
            __builtin_amdgcn_sched_barrier(0);
        }
        const int s0 = i % 3, s1 = (i + 1) % 3, s2 = (i + 2) % 3;
        rm[s2] = *(const v4f*)(Lm + (i + 2) * W);
        r0[s2] = *(const v4f*)(L0 + (i + 2) * W);
        rp[s2] = *(const v4f*)(Lp + (i + 2) * W);

        // separable: per-plane maxes over the 3 h-rows
        const v4f a3m = vmax4(vmax4(rm[s0], rm[s1]), rm[s2]);   // plane d-1, all rows
        const v4f a3p = vmax4(vmax4(rp[s0], rp[s1]), rp[s2]);   // plane d+1, all rows
        const v4f a20 = vmax4(r0[s0], r0[s2]);                  // plane d, h +- 1
        const v4f v8  = vmax4(vmax4(a3m, a3p), a20);            // 8 non-center rows
        const v4f c   = r0[s1];

        const float l8 = __shfl_up(v8.w, 1);     // lane0 garbage, masked
        const float r8 = __shfl_down(v8.x, 1);   // lane63 garbage, masked
        const float lc = __shfl_up(c.w, 1);
        const float rc = __shfl_down(c.x, 1);

        float n0 = fmaxf(fmaxf(l8,   v8.x), v8.y);
        float n1 = fmaxf(fmaxf(v8.x, v8.y), v8.z);
        float n2 = fmaxf(fmaxf(v8.y, v8.z), v8.w);
        float n3 = fmaxf(fmaxf(v8.z, v8.w), r8);
        n0 = fmaxf(n0, fmaxf(lc,  c.y));
        n1 = fmaxf(n1, fmaxf(c.x, c.z));
        n2 = fmaxf(n2, fmaxf(c.y, c.w));
        n3 = fmaxf(n3, fmaxf(c.z, rc));

        const int h = h0 + i;
        const bool hv = (h > 0) && (h < H - 1);   // wave-uniform
        const bool v  = hv && dv;
        v4f o;
        o.x = (v && lane > 0  && c.x > n0) ? c.x : 0.f;
        o.y = (v && c.y > n1) ? c.y : 0.f;
        o.z = (v && c.z > n2) ? c.z : 0.f;
        o.w = (v && lane < 63 && c.w > n3) ? c.w : 0.f;
        __builtin_nontemporal_store(o, (v4f*)(ovol + h * SH));
    }
}

extern "C" void kernel_launch(void* const* d_in, const int* in_sizes, int n_in,
                              void* d_out, int out_size, void* d_ws, size_t ws_size,
                              hipStream_t stream) {
    const float* x = (const float*)d_in[0];
    float* out = (float*)d_out;
    // blocks = BC * DG * HG = 16*8*32 = 4096, 256 threads each, 2 blocks/CU
    const int grid = BC * DG * HG;
    nms3d_kernel<<<grid, 256, 0, stream>>>(x, out);
}

// Round 11
// 223.986 us; speedup vs baseline: 1.0057x; 1.0057x over previous
//
#include <hip/hip_runtime.h>

// NMS3D (4,4,32,256,256) fp32, strict 26-neighbor max.
// R16b: resubmit of R16 (harness ExceptionGroup, no signal) with the
// break-in-unrolled-loop construct removed (4-iter loop + tail if).
// Design: R9's exact tile (36 KiB, 6 planes x 6 rows) at 512 threads/block
// -> full CU occupancy at UNCHANGED per-drain bytes.
// R15 closed manual pipelining: raw-barrier+asm-vmcnt kernels = 81-95us
// (R8/R12/R13/R15); plain stage->syncthreads->compute = 62-65us (R6/R9/R10),
// even at identical geometry (R15 82 vs R6 65) — the machinery itself costs
// more than the drain it hides.
// Residual model (R12 arithmetic): waves are phase-correlated (all stage/
// drain together), so TLP doesn't cover stalls; the one working lever is
// per-wait bytes (R9's 36 KiB/drain). Untested best cell of the
// {per-wait bytes x waves/CU} matrix: 36 KiB AND 32 waves/CU.
//   512 thr = 8 waves; waves stage 4-5 rows each; ONE syncthreads drain;
//   each wave computes 2 rows (R10's verified straight-line body);
//   4 blocks/CU x 36 KiB = 144 KiB LDS, 2048 threads = FULL occupancy.
//   __launch_bounds__(512,8) caps VGPR at 64 (8 waves/SIMD).
// Normal stores (R14 >= neutral; exit-drain acks at L2 not HBM).
// Math verified absmax 0.0 in R6-R15: separable vertical max + lane shuffles.

typedef float v4f __attribute__((ext_vector_type(4)));

constexpr int W  = 256;
constexpr int H  = 256;
constexpr int D  = 32;
constexpr int SH = W;
constexpr int SD = W * H;
constexpr int KD = 4;                  // d outputs per block
constexpr int HC = 4;                  // h output rows per block
constexpr int BC = 16;                 // B*CH
constexpr int DG = D / KD;             // 8
constexpr int HG = H / HC;             // 64
constexpr int NPL = KD + 2;            // 6 staged planes
constexpr int NR  = HC + 2;            // 6 staged rows per plane
constexpr int TROWS = NPL * NR;        // 36 rows of W floats = 36 KiB

__device__ __forceinline__ v4f vmax4(v4f a, v4f b) {
    return (v4f){fmaxf(a.x, b.x), fmaxf(a.y, b.y), fmaxf(a.z, b.z), fmaxf(a.w, b.w)};
}

__device__ __forceinline__ void stage_row(const float* __restrict__ vol,
                                          float* lds, int t, int d0, int h0,
                                          int lane) {
    const int j = t / NR;
    const int r = t - j * NR;
    int p = d0 - 1 + j;  p = p < 0 ? 0 : (p > D - 1 ? D - 1 : p);
    int hh = h0 - 1 + r; hh = hh < 0 ? 0 : (hh > H - 1 ? H - 1 : hh);
    const float* gp = vol + p * SD + hh * SH + (lane << 2);
    // lane i's 16B land at ldsbase + 16*i -> exactly row-major row layout
    __builtin_amdgcn_global_load_lds(
        (const __attribute__((address_space(1))) unsigned int*)gp,
        (__attribute__((address_space(3))) unsigned int*)&lds[(j * NR + r) * W],
        16, 0, 0);
}

// One output row from its 9 staged rows (3 h-rows x 3 planes). Verified
// (absmax 0.0, R6-R15): separable vertical max, lane shuffles for w-edges.
__device__ __forceinline__ v4f nms_row(v4f m0, v4f m1, v4f m2,
                                       v4f c0, v4f c1, v4f c2,
                                       v4f p0, v4f p1, v4f p2,
                                       bool valid, int lane) {
    const v4f a3m = vmax4(vmax4(m0, m1), m2);   // plane d-1, all 3 rows
    const v4f a3p = vmax4(vmax4(p0, p1), p2);   // plane d+1, all 3 rows
    const v4f a20 = vmax4(c0, c2);              // plane d, h +- 1
    const v4f v8  = vmax4(vmax4(a3m, a3p), a20);
    const v4f c   = c1;

    const float l8 = __shfl_up(v8.w, 1);     // lane0 garbage, masked below
    const float r8 = __shfl_down(v8.x, 1);   // lane63 garbage, masked below
    const float lc = __shfl_up(c.w, 1);
    const float rc = __shfl_down(c.x, 1);

    float n0 = fmaxf(fmaxf(l8,   v8.x), v8.y);
    float n1 = fmaxf(fmaxf(v8.x, v8.y), v8.z);
    float n2 = fmaxf(fmaxf(v8.y, v8.z), v8.w);
    float n3 = fmaxf(fmaxf(v8.z, v8.w), r8);
    n0 = fmaxf(n0, fmaxf(lc,  c.y));
    n1 = fmaxf(n1, fmaxf(c.x, c.z));
    n2 = fmaxf(n2, fmaxf(c.y, c.w));
    n3 = fmaxf(n3, fmaxf(c.z, rc));

    v4f o;
    o.x = (valid && lane > 0  && c.x > n0) ? c.x : 0.f;
    o.y = (valid && c.y > n1) ? c.y : 0.f;
    o.z = (valid && c.z > n2) ? c.z : 0.f;
    o.w = (valid && lane < 63 && c.w > n3) ? c.w : 0.f;
    return o;
}

__global__ __launch_bounds__(512, 8) void nms3d_kernel(const float* __restrict__ x,
                                                       float* __restrict__ out) {
    __shared__ float lds[TROWS * W];   // 36 KiB -> 4 blocks/CU at 512 thr

    const int blk  = blockIdx.x;
    const int wv   = threadIdx.x >> 6;   // 0..7
    const int lane = threadIdx.x & 63;
    const int hc   = blk & (HG - 1);            // fastest: h-neighbors share halo in L2
    const int dg   = (blk >> 6) & (DG - 1);
    const int bc   = blk >> 9;
    const int d0   = dg * KD;
    const int h0   = hc * HC;

    const float* vol = x + bc * (D * SD);

    // ---- stage 36 rows over 8 waves: wv stages t = wv*4..wv*4+3; waves 0..3
    //      additionally stage t = 32+wv. No break inside unrolled loop. ----
    #pragma unroll
    for (int u = 0; u < 4; ++u)
        stage_row(vol, lds, wv * 4 + u, d0, h0, lane);
    if (wv < 4)
        stage_row(vol, lds, 32 + wv, d0, h0, lane);
    __syncthreads();   // drains vmcnt (DMA) then barrier — the block's only sync

    // ---- compute: wave wv -> plane d0 + (wv>>1), rows rw = (wv&1)*2 .. +1 ----
    const int pi = wv >> 1;              // 0..3: output plane within block
    const int rw = (wv & 1) * 2;         // 0 or 2: first output row within block
    const int d  = d0 + pi;
    const bool dv = (d > 0) && (d < D - 1);
    const int h  = h0 + rw;
    const bool hv0 = (h > 0) && (h < H - 1);      // wave-uniform
    const bool hv1 = (h + 1 < H - 1);             // h+1 >= 1 always

    const float* Lm = lds + (pi * NR + rw) * W + (lane << 2);  // plane d-1, row rw
    const float* L0 = Lm + NR * W;                             // plane d
    const float* Lp = L0 + NR * W;                             // plane d+1

    // staged rows rw..rw+3 of each plane feed output rows rw, rw+1
    const v4f m0 = *(const v4f*)(Lm + 0 * W), m1 = *(const v4f*)(Lm + 1 * W);
    const v4f m2 = *(const v4f*)(Lm + 2 * W), m3 = *(const v4f*)(Lm + 3 * W);
    const v4f c0 = *(const v4f*)(L0 + 0 * W), c1 = *(const v4f*)(L0 + 1 * W);
    const v4f c2 = *(const v4f*)(L0 + 2 * W), c3 = *(const v4f*)(L0 + 3 * W);
    const v4f p0 = *(const v4f*)(Lp + 0 * W), p1 = *(const v4f*)(Lp + 1 * W);
    const v4f p2 = *(const v4f*)(Lp + 2 * W), p3 = *(const v4f*)(Lp + 3 * W);

    float* orow = out + bc * (D * SD) + d * SD + h * SH + (lane << 2);
    const v4f o0 = nms_row(m0, m1, m2, c0, c1, c2, p0, p1, p2, hv0 && dv, lane);
    *(v4f*)orow = o0;                               // normal store (R14)
    const v4f o1 = nms_row(m1, m2, m3, c1, c2, c3, p1, p2, p3, hv1 && dv, lane);
    *(v4f*)(orow + SH) = o1;
}

extern "C" void kernel_launch(void* const* d_in, const int* in_sizes, int n_in,
                              void* d_out, int out_size, void* d_ws, size_t ws_size,
                              hipStream_t stream) {
    const float* x = (const float*)d_in[0];
    float* out = (float*)d_out;
    // blocks = BC * DG * HG = 16*8*64 = 8192, 512 threads each, 4 blocks/CU
    const int grid = BC * DG * HG;
    nms3d_kernel<<<grid, 512, 0, stream>>>(x, out);
}